// Round 4
// baseline (285.585 us; speedup 1.0000x reference)
//
#include <hip/hip_runtime.h>

typedef __attribute__((ext_vector_type(8))) __bf16 bf16x8;
typedef __attribute__((ext_vector_type(4))) __bf16 bf16x4;
typedef __attribute__((ext_vector_type(4))) float f32x4;

__device__ __forceinline__ float fast_sig(float x) {
  return __builtin_amdgcn_rcpf(1.0f + __expf(-x));
}
__device__ __forceinline__ float siluf(float x) { return x * fast_sig(x); }
__device__ __forceinline__ __bf16 tobf(float x) { return (__bf16)x; }

// ================= k_prep: all weight transposes to bf16 [out][k] =================
__global__ __launch_bounds__(256) void k_prep(
    const float* __restrict__ We1, const float* __restrict__ Wx1,
    const float* __restrict__ We2, const float* __restrict__ Wx2,
    const float* __restrict__ Wh1, const float* __restrict__ Wh2,
    const float* __restrict__ invf,
    __bf16* __restrict__ wt_e, __bf16* __restrict__ wt_x,
    __bf16* __restrict__ w2e, __bf16* __restrict__ w2x,
    __bf16* __restrict__ wh1t, __bf16* __restrict__ wh2t,
    __bf16* __restrict__ hcat)
{
  int idx = blockIdx.x * 256 + threadIdx.x;          // 0..262143
  if (idx < 147456) {                                // [256 kk][576 f]
    int kk = idx / 576, f = idx - kk * 576;
    wt_e[idx] = tobf(We1[f * 256 + kk]);
    wt_x[idx] = tobf(Wx1[f * 256 + kk]);
  }
  if (idx < 65536) {                                 // [256 c][256 k]
    int c = idx >> 8, k = idx & 255;
    w2e[idx] = tobf(We2[k * 256 + c]);
    w2x[idx] = tobf(Wx2[k * 256 + c]);
    wh2t[idx] = tobf(Wh2[k * 256 + c]);
  }
  if (idx < 131072) {                                // [256 c][512 k]
    int c = idx >> 9, k = idx & 511;
    wh1t[idx] = tobf(Wh1[k * 256 + c]);
  }
  {                                                  // hcat[:,0:256] = bf16(invf)
    int node = idx >> 8, k = idx & 255;
    hcat[node * 512 + k] = tobf(invf[idx]);
  }
}

// ============ generic node GEMM: 64-row tile, 256 thr, out[c][node], no LDS ============
template<int NKS>
__device__ __forceinline__ void node_gemm64(
    const __bf16* __restrict__ B, int ldb, int boff,
    const __bf16* __restrict__ A, int lda, int aoff,
    int row0, int tid, f32x4 acc[4][4])
{
  const int lane = tid & 63, wc = tid >> 6, lr = lane & 15, lg = lane >> 4;
  #pragma unroll
  for (int ks = 0; ks < NKS; ks++) {
    bf16x8 bB[4], aA[4];
    #pragma unroll
    for (int m = 0; m < 4; m++)
      bB[m] = *(const bf16x8*)(B + (size_t)(row0 + m * 16 + lr) * ldb + boff + ks * 32 + lg * 8);
    #pragma unroll
    for (int n = 0; n < 4; n++)
      aA[n] = *(const bf16x8*)(A + (size_t)(wc * 64 + n * 16 + lr) * lda + aoff + ks * 32 + lg * 8);
    #pragma unroll
    for (int m = 0; m < 4; m++)
      #pragma unroll
      for (int n = 0; n < 4; n++)
        acc[m][n] = __builtin_amdgcn_mfma_f32_16x16x32_bf16(aA[n], bB[m], acc[m][n], 0, 0, 0);
  }
}

// ================= node projections (4 mats) =================
__global__ __launch_bounds__(256) void k_nproj(
    const __bf16* __restrict__ hcat,
    const __bf16* __restrict__ wt_e, const __bf16* __restrict__ wt_x,
    const float* __restrict__ be1, const float* __restrict__ bx1,
    float* __restrict__ hie, float* __restrict__ hje,
    float* __restrict__ hix, float* __restrict__ hjx)
{
  const int tid = threadIdx.x;
  const int row0 = blockIdx.x * 64;
  const int mat = blockIdx.y;
  const __bf16* A = (mat < 2) ? wt_e : wt_x;
  const int aoff = (mat & 1) ? 256 : 0;
  const float* bias = (mat == 0) ? be1 : (mat == 2 ? bx1 : nullptr);
  float* out = (mat == 0) ? hie : (mat == 1) ? hje : (mat == 2) ? hix : hjx;

  f32x4 acc[4][4];
  #pragma unroll
  for (int m = 0; m < 4; m++)
    #pragma unroll
    for (int n = 0; n < 4; n++) { f32x4 z = {0.f,0.f,0.f,0.f}; acc[m][n] = z; }
  node_gemm64<8>(hcat, 512, 0, A, 576, aoff, row0, tid, acc);

  const int lane = tid & 63, wc = tid >> 6, lr = lane & 15, lg = lane >> 4;
  #pragma unroll
  for (int m = 0; m < 4; m++) {
    int node = row0 + m * 16 + lr;
    #pragma unroll
    for (int n = 0; n < 4; n++) {
      int c0 = wc * 64 + n * 16 + lg * 4;
      f32x4 v = acc[m][n];
      if (bias) v += *(const f32x4*)(bias + c0);
      *(f32x4*)(out + (size_t)node * 256 + c0) = v;
    }
  }
}

// ================= h-path GEMM1: h1 = silu(hcat @ Wh1 + bh1), bf16 out =================
__global__ __launch_bounds__(256) void k_h1(
    const __bf16* __restrict__ hcat, const __bf16* __restrict__ wh1t,
    const float* __restrict__ bh1, __bf16* __restrict__ h1b)
{
  const int tid = threadIdx.x;
  const int row0 = blockIdx.x * 64;
  f32x4 acc[4][4];
  #pragma unroll
  for (int m = 0; m < 4; m++)
    #pragma unroll
    for (int n = 0; n < 4; n++) { f32x4 z = {0.f,0.f,0.f,0.f}; acc[m][n] = z; }
  node_gemm64<16>(hcat, 512, 0, wh1t, 512, 0, row0, tid, acc);

  const int lane = tid & 63, wc = tid >> 6, lr = lane & 15, lg = lane >> 4;
  #pragma unroll
  for (int m = 0; m < 4; m++) {
    int node = row0 + m * 16 + lr;
    #pragma unroll
    for (int n = 0; n < 4; n++) {
      int c0 = wc * 64 + n * 16 + lg * 4;
      f32x4 b4 = *(const f32x4*)(bh1 + c0);
      bf16x4 pk;
      #pragma unroll
      for (int r = 0; r < 4; r++) pk[r] = tobf(siluf(acc[m][n][r] + b4[r]));
      *(bf16x4*)(h1b + (size_t)node * 256 + c0) = pk;
    }
  }
}

// ===== h-path GEMM2 + mask + coord finalize =====
__global__ __launch_bounds__(256) void k_h2(
    const __bf16* __restrict__ h1b, const __bf16* __restrict__ wh2t,
    const float* __restrict__ bh2, const float* __restrict__ amask,
    const float* __restrict__ coords, const float* __restrict__ cupd,
    float* __restrict__ out_feats, float* __restrict__ out_coords)
{
  __shared__ float sM[2];
  const int tid = threadIdx.x;
  const int row0 = blockIdx.x * 64;
  const int b = row0 >> 7;
  f32x4 acc[4][4];
  #pragma unroll
  for (int m = 0; m < 4; m++)
    #pragma unroll
    for (int n = 0; n < 4; n++) { f32x4 z = {0.f,0.f,0.f,0.f}; acc[m][n] = z; }
  node_gemm64<8>(h1b, 256, 0, wh2t, 256, 0, row0, tid, acc);

  if (tid < 128) {
    float v = amask[b * 128 + tid];
    #pragma unroll
    for (int off = 1; off < 64; off <<= 1) v += __shfl_xor(v, off);
    if ((tid & 63) == 0) sM[tid >> 6] = v;
  }
  __syncthreads();
  const float sNum = sM[0] + sM[1];

  const int lane = tid & 63, wc = tid >> 6, lr = lane & 15, lg = lane >> 4;
  #pragma unroll
  for (int m = 0; m < 4; m++) {
    int node = row0 + m * 16 + lr;
    float msk = amask[node];
    #pragma unroll
    for (int n = 0; n < 4; n++) {
      int c0 = wc * 64 + n * 16 + lg * 4;
      f32x4 b4 = *(const f32x4*)(bh2 + c0);
      f32x4 v = (acc[m][n] + b4) * msk;
      *(f32x4*)(out_feats + (size_t)node * 256 + c0) = v;
    }
  }
  if (tid < 192) {
    int nl = tid / 3, d = tid - nl * 3;
    int node = row0 + nl;
    float upd = cupd[node * 3 + d] / (sNum + 1.0f);
    out_coords[node * 3 + d] = (coords[node * 3 + d] + upd) * amask[node];
  }
}

// ================= edge-MLP path: processes j in two 64-row halves =================
template<bool EPATH>
__device__ __forceinline__ void egnn_path(
    int tid,
    const __bf16* sE, char* sSb,
    const float* shi, const float* slast, const float* sqv, const float* sAdj,
    const float* __restrict__ hjb,          // + b*128*256
    const __bf16* __restrict__ wt,          // [256 kk][576 f]
    const __bf16* __restrict__ w2,          // [256 c][256 k]
    const float* __restrict__ bias2,
    const float* __restrict__ vvec,
    float* sRed,                            // [128] (two halves)
    float batt0,                            // b_att (e) / b_x3 (x)
    float* sNM, float* sCup,
    const float* __restrict__ coords, int b,
    float cix, float ciy, float ciz)
{
  const int lane = tid & 63, w = tid >> 6;
  const int lr = lane & 15, lg = lane >> 4;
  const int cg = (w & 7) * 32;     // kk (GEMM1) / c (GEMM2) group base
  const int jg = (w >> 3) * 32;    // local j group base within 64-half

  #pragma unroll
  for (int half = 0; half < 2; half++) {
    // ---- GEMM1: S'[kk][j], K=64 ----
    f32x4 acc[2][2];
    #pragma unroll
    for (int m = 0; m < 2; m++)
      #pragma unroll
      for (int n = 0; n < 2; n++) { f32x4 z = {0.f,0.f,0.f,0.f}; acc[m][n] = z; }
    #pragma unroll
    for (int ks = 0; ks < 2; ks++) {
      bf16x8 bE[2];
      #pragma unroll
      for (int m = 0; m < 2; m++)
        bE[m] = *(const bf16x8*)(sE + (half * 64 + jg + m * 16 + lr) * 72 + ks * 32 + lg * 8);
      #pragma unroll
      for (int n = 0; n < 2; n++) {
        bf16x8 aW = *(const bf16x8*)(wt + (size_t)(cg + n * 16 + lr) * 576 + 512 + ks * 32 + lg * 8);
        #pragma unroll
        for (int m = 0; m < 2; m++)
          acc[m][n] = __builtin_amdgcn_mfma_f32_16x16x32_bf16(aW, bE[m], acc[m][n], 0, 0, 0);
      }
    }
    // ep1: + hi + hj + sq*w_last, silu, bf16 -> swizzled sSb
    #pragma unroll
    for (int m = 0; m < 2; m++) {
      const int jl = jg + m * 16 + lr;
      const int jh = half * 64 + jl;
      const float sq = sqv[jh];
      #pragma unroll
      for (int n = 0; n < 2; n++) {
        const int kk0 = cg + n * 16 + lg * 4;
        f32x4 hj4 = *(const f32x4*)(hjb + (size_t)jh * 256 + kk0);
        f32x4 hi4 = *(const f32x4*)(shi + kk0);
        f32x4 sl4 = *(const f32x4*)(slast + kk0);
        bf16x4 pk;
        #pragma unroll
        for (int r = 0; r < 4; r++)
          pk[r] = tobf(siluf(acc[m][n][r] + hi4[r] + hj4[r] + sq * sl4[r]));
        int off = (jl * 512 + kk0 * 2) ^ ((jl & 7) << 4);
        *(bf16x4*)(sSb + off) = pk;
      }
    }
    __syncthreads();

    // ---- GEMM2: M'[c][j], K=256 ----
    #pragma unroll
    for (int m = 0; m < 2; m++)
      #pragma unroll
      for (int n = 0; n < 2; n++) { f32x4 z = {0.f,0.f,0.f,0.f}; acc[m][n] = z; }
    #pragma unroll
    for (int ks = 0; ks < 8; ks++) {
      bf16x8 bS[2];
      #pragma unroll
      for (int m = 0; m < 2; m++) {
        const int jl = jg + m * 16 + lr;
        int off = (jl * 512 + (ks * 32 + lg * 8) * 2) ^ ((jl & 7) << 4);
        bS[m] = *(const bf16x8*)(sSb + off);
      }
      #pragma unroll
      for (int n = 0; n < 2; n++) {
        bf16x8 aW = *(const bf16x8*)(w2 + (size_t)(cg + n * 16 + lr) * 256 + ks * 32 + lg * 8);
        #pragma unroll
        for (int m = 0; m < 2; m++)
          acc[m][n] = __builtin_amdgcn_mfma_f32_16x16x32_bf16(aW, bS[m], acc[m][n], 0, 0, 0);
      }
    }
    // ep2: silu(+bias2), dot with vvec -> sRed[half j]
    float p[2] = {0.f, 0.f};
    #pragma unroll
    for (int n = 0; n < 2; n++) {
      f32x4 bb = *(const f32x4*)(bias2 + cg + n * 16 + lg * 4);
      f32x4 vv = *(const f32x4*)(vvec  + cg + n * 16 + lg * 4);
      #pragma unroll
      for (int m = 0; m < 2; m++)
        #pragma unroll
        for (int r = 0; r < 4; r++) {
          float s = siluf(acc[m][n][r] + bb[r]);
          acc[m][n][r] = s;
          p[m] += s * vv[r];
        }
    }
    #pragma unroll
    for (int m = 0; m < 2; m++) {
      p[m] += __shfl_xor(p[m], 16);
      p[m] += __shfl_xor(p[m], 32);
    }
    if (lane < 16) {
      #pragma unroll
      for (int m = 0; m < 2; m++)
        atomicAdd(&sRed[half * 64 + jg + m * 16 + lr], p[m]);
    }
    __syncthreads();

    // ---- att / coord phase (registers + post-barrier LDS only; overlaps next GEMM1) ----
    if constexpr (EPATH) {
      float aw[2];
      #pragma unroll
      for (int m = 0; m < 2; m++) {
        int jh = half * 64 + jg + m * 16 + lr;
        aw[m] = fast_sig(sRed[jh] + batt0) * sAdj[jh];
      }
      f32x4 q[2];
      #pragma unroll
      for (int n = 0; n < 2; n++) { f32x4 z = {0.f,0.f,0.f,0.f}; q[n] = z; }
      #pragma unroll
      for (int m = 0; m < 2; m++)
        #pragma unroll
        for (int n = 0; n < 2; n++)
          q[n] += acc[m][n] * aw[m];
      #pragma unroll
      for (int off = 1; off < 16; off <<= 1)
        #pragma unroll
        for (int n = 0; n < 2; n++)
          #pragma unroll
          for (int r = 0; r < 4; r++)
            q[n][r] += __shfl_xor(q[n][r], off);
      if (lr == 0) {
        #pragma unroll
        for (int n = 0; n < 2; n++)
          #pragma unroll
          for (int r = 0; r < 4; r++)
            atomicAdd(&sNM[cg + n * 16 + lg * 4 + r], q[n][r]);
      }
    } else {
      if (tid < 64) {
        int jh = half * 64 + tid;
        int jgl = b * 128 + jh;
        float ea = sRed[jh] + batt0;
        float wgt = ea * __builtin_amdgcn_rcpf(sqrtf(sqv[jh] + 1e-5f) + 1.0f) * sAdj[jh];
        float wx = wgt * (cix - coords[jgl * 3 + 0]);
        float wy = wgt * (ciy - coords[jgl * 3 + 1]);
        float wz = wgt * (ciz - coords[jgl * 3 + 2]);
        #pragma unroll
        for (int off = 1; off < 64; off <<= 1) {
          wx += __shfl_xor(wx, off);
          wy += __shfl_xor(wy, off);
          wz += __shfl_xor(wz, off);
        }
        if (tid == 0) {
          atomicAdd(&sCup[0], wx);
          atomicAdd(&sCup[1], wy);
          atomicAdd(&sCup[2], wz);
        }
      }
    }
  }
}

// ================= main edge kernel: one block = one (b,i), 1024 thr, 2 blocks/CU =================
__global__ __launch_bounds__(1024, 8) void k_edge(
    const float* __restrict__ coords, const float* __restrict__ adjm,
    const float* __restrict__ ef,
    const float* __restrict__ We1, const float* __restrict__ Wx1,
    const float* __restrict__ batt,
    const float* __restrict__ be2, const float* __restrict__ bx2,
    const float* __restrict__ bx3,
    const float* __restrict__ Watt, const float* __restrict__ Wx3,
    const float* __restrict__ hie, const float* __restrict__ hje,
    const float* __restrict__ hix, const float* __restrict__ hjx,
    const __bf16* __restrict__ wt_e, const __bf16* __restrict__ wt_x,
    const __bf16* __restrict__ w2e, const __bf16* __restrict__ w2x,
    __bf16* __restrict__ hcat, float* __restrict__ cupd)
{
  __shared__ __align__(16) __bf16 sE[128 * 72];          // 18 KB
  __shared__ __align__(16) char sSb[64 * 512];           // 32 KB (one j-half)
  __shared__ float shie[256], shix[256], slaste[256], slastx[256];
  __shared__ float sqv[128], sAdj[128], sRedE[128], sRedX[128], sNM[256], sCup[4];

  const int tid = threadIdx.x;
  const int bi = blockIdx.x;
  const int b = bi >> 7;

  const float cix = coords[bi * 3 + 0];
  const float ciy = coords[bi * 3 + 1];
  const float ciz = coords[bi * 3 + 2];

  if (tid < 128) { sRedE[tid] = 0.f; sRedX[tid] = 0.f; }
  else if (tid < 384) sNM[tid - 128] = 0.f;
  else if (tid < 388) sCup[tid - 384] = 0.f;
  if (tid < 256) {
    shie[tid] = hie[(size_t)bi * 256 + tid];
    shix[tid] = hix[(size_t)bi * 256 + tid];
    slaste[tid] = We1[576 * 256 + tid];
    slastx[tid] = Wx1[576 * 256 + tid];
  }
  if (tid >= 512 && tid < 640) {
    int j = tid - 512;
    int jg = b * 128 + j;
    float dx = cix - coords[jg * 3 + 0];
    float dy = ciy - coords[jg * 3 + 1];
    float dz = ciz - coords[jg * 3 + 2];
    sqv[j] = dx * dx + dy * dy + dz * dz;
  }
  if (tid >= 640 && tid < 768) {
    int j = tid - 640;
    sAdj[j] = adjm[(size_t)bi * 128 + j];
  }
  const float* efb = ef + (size_t)bi * 8192;
  #pragma unroll
  for (int it = 0; it < 2; it++) {
    int idx = (tid + it * 1024) * 4;
    f32x4 v = *(const f32x4*)(efb + idx);
    bf16x4 pk;
    pk[0] = tobf(v[0]); pk[1] = tobf(v[1]); pk[2] = tobf(v[2]); pk[3] = tobf(v[3]);
    *(bf16x4*)(sE + (idx >> 6) * 72 + (idx & 63)) = pk;
  }
  __syncthreads();

  egnn_path<true>(tid, sE, sSb, shie, slaste, sqv, sAdj,
                  hje + (size_t)b * 32768, wt_e, w2e, be2, Watt,
                  sRedE, batt[0], sNM, sCup, coords, b, cix, ciy, ciz);
  egnn_path<false>(tid, sE, sSb, shix, slastx, sqv, sAdj,
                   hjx + (size_t)b * 32768, wt_x, w2x, bx2, Wx3,
                   sRedX, bx3[0], sNM, sCup, coords, b, cix, ciy, ciz);

  __syncthreads();
  if (tid < 256) hcat[(size_t)bi * 512 + 256 + tid] = tobf(sNM[tid]);
  if (tid < 3) cupd[bi * 3 + tid] = sCup[tid];
}

extern "C" void kernel_launch(void* const* d_in, const int* in_sizes, int n_in,
                              void* d_out, int out_size, void* d_ws, size_t ws_size,
                              hipStream_t stream)
{
  const float* coords = (const float*)d_in[0];
  const float* invf  = (const float*)d_in[1];
  const float* adjm  = (const float*)d_in[2];
  const float* amask = (const float*)d_in[3];
  const float* ef    = (const float*)d_in[4];
  const float* We1   = (const float*)d_in[5];
  const float* be1   = (const float*)d_in[6];
  const float* We2   = (const float*)d_in[7];
  const float* be2   = (const float*)d_in[8];
  const float* Watt  = (const float*)d_in[9];
  const float* batt  = (const float*)d_in[10];
  const float* Wh1   = (const float*)d_in[11];
  const float* bh1   = (const float*)d_in[12];
  const float* Wh2   = (const float*)d_in[13];
  const float* bh2   = (const float*)d_in[14];
  const float* Wx1   = (const float*)d_in[15];
  const float* bx1   = (const float*)d_in[16];
  const float* Wx2   = (const float*)d_in[17];
  const float* bx2   = (const float*)d_in[18];
  const float* Wx3   = (const float*)d_in[19];
  const float* bx3   = (const float*)d_in[20];

  char* ws = (char*)d_ws;
  const size_t MB = 1u << 20;
  float* hie  = (float*)(ws + 0 * MB);
  float* hje  = (float*)(ws + 1 * MB);
  float* hix  = (float*)(ws + 2 * MB);
  float* hjx  = (float*)(ws + 3 * MB);
  __bf16* hcat = (__bf16*)(ws + 4 * MB);              // [1024][512]
  __bf16* h1b  = (__bf16*)(ws + 5 * MB);              // [1024][256]
  __bf16* wt_e = (__bf16*)(ws + 5 * MB + 524288);     // [256][576]
  __bf16* wt_x = (__bf16*)(ws + 5 * MB + 524288 + 294912);
  __bf16* w2e  = (__bf16*)(ws + 5 * MB + 524288 + 2 * 294912);
  __bf16* w2x  = (__bf16*)(ws + 5 * MB + 524288 + 2 * 294912 + 131072);
  __bf16* wh1t = (__bf16*)(ws + 5 * MB + 524288 + 2 * 294912 + 2 * 131072);
  __bf16* wh2t = (__bf16*)(ws + 5 * MB + 524288 + 2 * 294912 + 2 * 131072 + 262144);
  float* cupd  = (float*)(ws + 5 * MB + 524288 + 2 * 294912 + 3 * 131072 + 262144);

  float* out_coords = (float*)d_out;
  float* out_feats  = out_coords + 8 * 128 * 3;

  hipLaunchKernelGGL(k_prep, dim3(1024), dim3(256), 0, stream,
                     We1, Wx1, We2, Wx2, Wh1, Wh2, invf,
                     wt_e, wt_x, w2e, w2x, wh1t, wh2t, hcat);
  hipLaunchKernelGGL(k_nproj, dim3(16, 4), dim3(256), 0, stream,
                     hcat, wt_e, wt_x, be1, bx1, hie, hje, hix, hjx);
  hipLaunchKernelGGL(k_edge, dim3(1024), dim3(1024), 0, stream,
                     coords, adjm, ef, We1, Wx1, batt, be2, bx2, bx3, Watt, Wx3,
                     hie, hje, hix, hjx, wt_e, wt_x, w2e, w2x, hcat, cupd);
  hipLaunchKernelGGL(k_h1, dim3(16), dim3(256), 0, stream,
                     hcat, wh1t, bh1, h1b);
  hipLaunchKernelGGL(k_h2, dim3(16), dim3(256), 0, stream,
                     h1b, wh2t, bh2, amask, coords, cupd, out_feats, out_coords);
}

// Round 5
// 252.995 us; speedup vs baseline: 1.1288x; 1.1288x over previous
//
#include <hip/hip_runtime.h>

typedef __attribute__((ext_vector_type(8))) __bf16 bf16x8;
typedef __attribute__((ext_vector_type(4))) __bf16 bf16x4;
typedef __attribute__((ext_vector_type(4))) float f32x4;

__device__ __forceinline__ float fast_sig(float x) {
  return __builtin_amdgcn_rcpf(1.0f + __expf(-x));
}
__device__ __forceinline__ float siluf(float x) { return x * fast_sig(x); }
__device__ __forceinline__ __bf16 tobf(float x) { return (__bf16)x; }

// ================= k_prep: weight transposes to bf16 [out][k] + WS zeroing =================
__global__ __launch_bounds__(256) void k_prep(
    const float* __restrict__ We1, const float* __restrict__ Wx1,
    const float* __restrict__ We2, const float* __restrict__ Wx2,
    const float* __restrict__ Wh1, const float* __restrict__ Wh2,
    const float* __restrict__ invf,
    __bf16* __restrict__ wt_e, __bf16* __restrict__ wt_x,
    __bf16* __restrict__ w2e, __bf16* __restrict__ w2x,
    __bf16* __restrict__ wh1t, __bf16* __restrict__ wh2t,
    __bf16* __restrict__ hcat,
    float* __restrict__ nmsg, float* __restrict__ cupd)
{
  int idx = blockIdx.x * 256 + threadIdx.x;          // 0..262143
  if (idx < 147456) {                                // [256 kk][576 f]
    int kk = idx / 576, f = idx - kk * 576;
    wt_e[idx] = tobf(We1[f * 256 + kk]);
    wt_x[idx] = tobf(Wx1[f * 256 + kk]);
  }
  if (idx < 65536) {                                 // [256 c][256 k]
    int c = idx >> 8, k = idx & 255;
    w2e[idx] = tobf(We2[k * 256 + c]);
    w2x[idx] = tobf(Wx2[k * 256 + c]);
    wh2t[idx] = tobf(Wh2[k * 256 + c]);
    f32x4 z = {0.f, 0.f, 0.f, 0.f};
    *(f32x4*)(nmsg + idx * 4) = z;                   // zero nmsg (262144 floats)
  }
  if (idx < 131072) {                                // [256 c][512 k]
    int c = idx >> 9, k = idx & 511;
    wh1t[idx] = tobf(Wh1[k * 256 + c]);
  }
  if (idx < 3072) cupd[idx] = 0.f;
  {                                                  // hcat[:,0:256] = bf16(invf)
    int node = idx >> 8, k = idx & 255;
    hcat[node * 512 + k] = tobf(invf[idx]);
  }
}

// ============ generic node GEMM: 64-row tile, 256 thr, out[c][node], no LDS ============
template<int NKS>
__device__ __forceinline__ void node_gemm64(
    const __bf16* __restrict__ B, int ldb, int boff,
    const __bf16* __restrict__ A, int lda, int aoff,
    int row0, int tid, f32x4 acc[4][4])
{
  const int lane = tid & 63, wc = tid >> 6, lr = lane & 15, lg = lane >> 4;
  #pragma unroll
  for (int ks = 0; ks < NKS; ks++) {
    bf16x8 bB[4], aA[4];
    #pragma unroll
    for (int m = 0; m < 4; m++)
      bB[m] = *(const bf16x8*)(B + (size_t)(row0 + m * 16 + lr) * ldb + boff + ks * 32 + lg * 8);
    #pragma unroll
    for (int n = 0; n < 4; n++)
      aA[n] = *(const bf16x8*)(A + (size_t)(wc * 64 + n * 16 + lr) * lda + aoff + ks * 32 + lg * 8);
    #pragma unroll
    for (int m = 0; m < 4; m++)
      #pragma unroll
      for (int n = 0; n < 4; n++)
        acc[m][n] = __builtin_amdgcn_mfma_f32_16x16x32_bf16(aA[n], bB[m], acc[m][n], 0, 0, 0);
  }
}

// ================= node projections (4 mats) =================
__global__ __launch_bounds__(256) void k_nproj(
    const __bf16* __restrict__ hcat,
    const __bf16* __restrict__ wt_e, const __bf16* __restrict__ wt_x,
    const float* __restrict__ be1, const float* __restrict__ bx1,
    float* __restrict__ hie, float* __restrict__ hje,
    float* __restrict__ hix, float* __restrict__ hjx)
{
  const int tid = threadIdx.x;
  const int row0 = blockIdx.x * 64;
  const int mat = blockIdx.y;
  const __bf16* A = (mat < 2) ? wt_e : wt_x;
  const int aoff = (mat & 1) ? 256 : 0;
  const float* bias = (mat == 0) ? be1 : (mat == 2 ? bx1 : nullptr);
  float* out = (mat == 0) ? hie : (mat == 1) ? hje : (mat == 2) ? hix : hjx;

  f32x4 acc[4][4];
  #pragma unroll
  for (int m = 0; m < 4; m++)
    #pragma unroll
    for (int n = 0; n < 4; n++) { f32x4 z = {0.f,0.f,0.f,0.f}; acc[m][n] = z; }
  node_gemm64<8>(hcat, 512, 0, A, 576, aoff, row0, tid, acc);

  const int lane = tid & 63, wc = tid >> 6, lr = lane & 15, lg = lane >> 4;
  #pragma unroll
  for (int m = 0; m < 4; m++) {
    int node = row0 + m * 16 + lr;
    #pragma unroll
    for (int n = 0; n < 4; n++) {
      int c0 = wc * 64 + n * 16 + lg * 4;
      f32x4 v = acc[m][n];
      if (bias) v += *(const f32x4*)(bias + c0);
      *(f32x4*)(out + (size_t)node * 256 + c0) = v;
    }
  }
}

// ================= k_mid: nmsg fp32 -> hcat upper half bf16 =================
__global__ __launch_bounds__(256) void k_mid(
    const float* __restrict__ nmsg, __bf16* __restrict__ hcat)
{
  int idx = blockIdx.x * 256 + threadIdx.x;   // 262144
  int node = idx >> 8, k = idx & 255;
  hcat[node * 512 + 256 + k] = tobf(nmsg[idx]);
}

// ================= h-path GEMM1 =================
__global__ __launch_bounds__(256) void k_h1(
    const __bf16* __restrict__ hcat, const __bf16* __restrict__ wh1t,
    const float* __restrict__ bh1, __bf16* __restrict__ h1b)
{
  const int tid = threadIdx.x;
  const int row0 = blockIdx.x * 64;
  f32x4 acc[4][4];
  #pragma unroll
  for (int m = 0; m < 4; m++)
    #pragma unroll
    for (int n = 0; n < 4; n++) { f32x4 z = {0.f,0.f,0.f,0.f}; acc[m][n] = z; }
  node_gemm64<16>(hcat, 512, 0, wh1t, 512, 0, row0, tid, acc);

  const int lane = tid & 63, wc = tid >> 6, lr = lane & 15, lg = lane >> 4;
  #pragma unroll
  for (int m = 0; m < 4; m++) {
    int node = row0 + m * 16 + lr;
    #pragma unroll
    for (int n = 0; n < 4; n++) {
      int c0 = wc * 64 + n * 16 + lg * 4;
      f32x4 b4 = *(const f32x4*)(bh1 + c0);
      bf16x4 pk;
      #pragma unroll
      for (int r = 0; r < 4; r++) pk[r] = tobf(siluf(acc[m][n][r] + b4[r]));
      *(bf16x4*)(h1b + (size_t)node * 256 + c0) = pk;
    }
  }
}

// ===== h-path GEMM2 + mask + coord finalize =====
__global__ __launch_bounds__(256) void k_h2(
    const __bf16* __restrict__ h1b, const __bf16* __restrict__ wh2t,
    const float* __restrict__ bh2, const float* __restrict__ amask,
    const float* __restrict__ coords, const float* __restrict__ cupd,
    float* __restrict__ out_feats, float* __restrict__ out_coords)
{
  __shared__ float sM[2];
  const int tid = threadIdx.x;
  const int row0 = blockIdx.x * 64;
  const int b = row0 >> 7;
  f32x4 acc[4][4];
  #pragma unroll
  for (int m = 0; m < 4; m++)
    #pragma unroll
    for (int n = 0; n < 4; n++) { f32x4 z = {0.f,0.f,0.f,0.f}; acc[m][n] = z; }
  node_gemm64<8>(h1b, 256, 0, wh2t, 256, 0, row0, tid, acc);

  if (tid < 128) {
    float v = amask[b * 128 + tid];
    #pragma unroll
    for (int off = 1; off < 64; off <<= 1) v += __shfl_xor(v, off);
    if ((tid & 63) == 0) sM[tid >> 6] = v;
  }
  __syncthreads();
  const float sNum = sM[0] + sM[1];

  const int lane = tid & 63, wc = tid >> 6, lr = lane & 15, lg = lane >> 4;
  #pragma unroll
  for (int m = 0; m < 4; m++) {
    int node = row0 + m * 16 + lr;
    float msk = amask[node];
    #pragma unroll
    for (int n = 0; n < 4; n++) {
      int c0 = wc * 64 + n * 16 + lg * 4;
      f32x4 b4 = *(const f32x4*)(bh2 + c0);
      f32x4 v = (acc[m][n] + b4) * msk;
      *(f32x4*)(out_feats + (size_t)node * 256 + c0) = v;
    }
  }
  if (tid < 192) {
    int nl = tid / 3, d = tid - nl * 3;
    int node = row0 + nl;
    float upd = cupd[node * 3 + d] / (sNum + 1.0f);
    out_coords[node * 3 + d] = (coords[node * 3 + d] + upd) * amask[node];
  }
}

// ================= edge-MLP path for one 64-j half (512 thr, 8 waves) =================
template<bool EPATH>
__device__ __forceinline__ void egnn_path(
    int tid,
    const __bf16* sE, char* sSb,
    const float* shi, const float* slast, const float* sqv, const float* sAdj,
    const float* __restrict__ hjb,          // + (b*128 + j0g)*256
    const __bf16* __restrict__ wt,          // [256 kk][576 f]
    const __bf16* __restrict__ w2,          // [256 c][256 k]
    const float* __restrict__ bias2,
    const float* __restrict__ vvec,
    float* sRed,                            // [64]
    float batt0,                            // b_att (e) / b_x3 (x)
    float* sNM, float* sCup,
    const float* __restrict__ coords, int jg0,  // global row base b*128+j0g
    float cix, float ciy, float ciz)
{
  const int lane = tid & 63, w = tid >> 6;
  const int lr = lane & 15, lg = lane >> 4;
  const int cg = (w & 3) * 64;     // c group base (4 waves cover 256)
  const int jw = (w >> 2) * 32;    // local j base (2 groups cover 64)

  // early-issue hj fragments (consumed in ep1)
  f32x4 hjf[2][4];
  #pragma unroll
  for (int m = 0; m < 2; m++) {
    const int jl = jw + m * 16 + lr;
    #pragma unroll
    for (int n = 0; n < 4; n++)
      hjf[m][n] = *(const f32x4*)(hjb + (size_t)jl * 256 + cg + n * 16 + lg * 4);
  }

  // ---- GEMM1: S'[kk][j], K=64 ----
  f32x4 acc[2][4];
  #pragma unroll
  for (int m = 0; m < 2; m++)
    #pragma unroll
    for (int n = 0; n < 4; n++) { f32x4 z = {0.f,0.f,0.f,0.f}; acc[m][n] = z; }
  #pragma unroll
  for (int ks = 0; ks < 2; ks++) {
    bf16x8 bE[2];
    #pragma unroll
    for (int m = 0; m < 2; m++)
      bE[m] = *(const bf16x8*)(sE + (jw + m * 16 + lr) * 72 + ks * 32 + lg * 8);
    #pragma unroll
    for (int n = 0; n < 4; n++) {
      bf16x8 aW = *(const bf16x8*)(wt + (size_t)(cg + n * 16 + lr) * 576 + 512 + ks * 32 + lg * 8);
      #pragma unroll
      for (int m = 0; m < 2; m++)
        acc[m][n] = __builtin_amdgcn_mfma_f32_16x16x32_bf16(aW, bE[m], acc[m][n], 0, 0, 0);
    }
  }
  // ep1: + hi + hj + sq*w_last, silu, bf16 -> swizzled sSb
  #pragma unroll
  for (int m = 0; m < 2; m++) {
    const int jl = jw + m * 16 + lr;
    const float sq = sqv[jl];
    #pragma unroll
    for (int n = 0; n < 4; n++) {
      const int kk0 = cg + n * 16 + lg * 4;
      f32x4 hi4 = *(const f32x4*)(shi + kk0);
      f32x4 sl4 = *(const f32x4*)(slast + kk0);
      bf16x4 pk;
      #pragma unroll
      for (int r = 0; r < 4; r++)
        pk[r] = tobf(siluf(acc[m][n][r] + hi4[r] + hjf[m][n][r] + sq * sl4[r]));
      int off = (jl * 512 + kk0 * 2) ^ ((jl & 7) << 4);
      *(bf16x4*)(sSb + off) = pk;
    }
  }
  __syncthreads();

  // ---- GEMM2: M'[c][j], K=256 ----
  #pragma unroll
  for (int m = 0; m < 2; m++)
    #pragma unroll
    for (int n = 0; n < 4; n++) { f32x4 z = {0.f,0.f,0.f,0.f}; acc[m][n] = z; }
  #pragma unroll
  for (int ks = 0; ks < 8; ks++) {
    bf16x8 bS[2];
    #pragma unroll
    for (int m = 0; m < 2; m++) {
      const int jl = jw + m * 16 + lr;
      int off = (jl * 512 + (ks * 32 + lg * 8) * 2) ^ ((jl & 7) << 4);
      bS[m] = *(const bf16x8*)(sSb + off);
    }
    #pragma unroll
    for (int n = 0; n < 4; n++) {
      bf16x8 aW = *(const bf16x8*)(w2 + (size_t)(cg + n * 16 + lr) * 256 + ks * 32 + lg * 8);
      #pragma unroll
      for (int m = 0; m < 2; m++)
        acc[m][n] = __builtin_amdgcn_mfma_f32_16x16x32_bf16(aW, bS[m], acc[m][n], 0, 0, 0);
    }
  }
  // ep2: silu(+bias2), dot with vvec -> sRed[j]
  float p[2] = {0.f, 0.f};
  #pragma unroll
  for (int n = 0; n < 4; n++) {
    f32x4 bb = *(const f32x4*)(bias2 + cg + n * 16 + lg * 4);
    f32x4 vv = *(const f32x4*)(vvec  + cg + n * 16 + lg * 4);
    #pragma unroll
    for (int m = 0; m < 2; m++)
      #pragma unroll
      for (int r = 0; r < 4; r++) {
        float s = siluf(acc[m][n][r] + bb[r]);
        acc[m][n][r] = s;
        p[m] += s * vv[r];
      }
  }
  #pragma unroll
  for (int m = 0; m < 2; m++) {
    p[m] += __shfl_xor(p[m], 16);
    p[m] += __shfl_xor(p[m], 32);
  }
  if (lane < 16) {
    #pragma unroll
    for (int m = 0; m < 2; m++)
      atomicAdd(&sRed[jw + m * 16 + lr], p[m]);
  }
  __syncthreads();

  // ---- att / coord phase (registers + sRed only) ----
  if constexpr (EPATH) {
    float aw[2];
    #pragma unroll
    for (int m = 0; m < 2; m++) {
      int jl = jw + m * 16 + lr;
      aw[m] = fast_sig(sRed[jl] + batt0) * sAdj[jl];
    }
    f32x4 q[4];
    #pragma unroll
    for (int n = 0; n < 4; n++) { f32x4 z = {0.f,0.f,0.f,0.f}; q[n] = z; }
    #pragma unroll
    for (int m = 0; m < 2; m++)
      #pragma unroll
      for (int n = 0; n < 4; n++)
        q[n] += acc[m][n] * aw[m];
    #pragma unroll
    for (int off = 1; off < 16; off <<= 1)
      #pragma unroll
      for (int n = 0; n < 4; n++)
        #pragma unroll
        for (int r = 0; r < 4; r++)
          q[n][r] += __shfl_xor(q[n][r], off);
    if (lr == 0) {
      #pragma unroll
      for (int n = 0; n < 4; n++)
        #pragma unroll
        for (int r = 0; r < 4; r++)
          atomicAdd(&sNM[cg + n * 16 + lg * 4 + r], q[n][r]);
    }
  } else {
    if (tid < 64) {
      int jl = tid;
      int jgl = jg0 + jl;
      float ea = sRed[jl] + batt0;
      float wgt = ea * __builtin_amdgcn_rcpf(sqrtf(sqv[jl] + 1e-5f) + 1.0f) * sAdj[jl];
      float wx = wgt * (cix - coords[jgl * 3 + 0]);
      float wy = wgt * (ciy - coords[jgl * 3 + 1]);
      float wz = wgt * (ciz - coords[jgl * 3 + 2]);
      #pragma unroll
      for (int off = 1; off < 64; off <<= 1) {
        wx += __shfl_xor(wx, off);
        wy += __shfl_xor(wy, off);
        wz += __shfl_xor(wz, off);
      }
      if (tid == 0) { sCup[0] = wx; sCup[1] = wy; sCup[2] = wz; }
    }
  }
}

// ======== main edge kernel: one block = one (b,i)-HALF (64 j), 512 thr ========
__global__ __launch_bounds__(512, 4) void k_edge(
    const float* __restrict__ coords, const float* __restrict__ adjm,
    const float* __restrict__ ef,
    const float* __restrict__ We1, const float* __restrict__ Wx1,
    const float* __restrict__ batt,
    const float* __restrict__ be2, const float* __restrict__ bx2,
    const float* __restrict__ bx3,
    const float* __restrict__ Watt, const float* __restrict__ Wx3,
    const float* __restrict__ hie, const float* __restrict__ hje,
    const float* __restrict__ hix, const float* __restrict__ hjx,
    const __bf16* __restrict__ wt_e, const __bf16* __restrict__ wt_x,
    const __bf16* __restrict__ w2e, const __bf16* __restrict__ w2x,
    float* __restrict__ nmsg, float* __restrict__ cupd)
{
  __shared__ __align__(16) __bf16 sE[64 * 72];           // 9 KB
  __shared__ __align__(16) char sSb[64 * 512];           // 32 KB
  __shared__ float shie[256], shix[256], slaste[256], slastx[256];
  __shared__ float sqv[64], sAdj[64], sRedE[64], sRedX[64], sNM[256], sCup[4];

  const int tid = threadIdx.x;
  const int bi = blockIdx.x >> 1;      // b*128 + i
  const int half = blockIdx.x & 1;
  const int b = bi >> 7;
  const int j0g = half * 64;
  const int jg0 = b * 128 + j0g;       // global row base of this half

  const float cix = coords[bi * 3 + 0];
  const float ciy = coords[bi * 3 + 1];
  const float ciz = coords[bi * 3 + 2];

  if (tid < 64) sRedE[tid] = 0.f;
  else if (tid < 128) sRedX[tid - 64] = 0.f;
  else if (tid < 384) sNM[tid - 128] = 0.f;
  else if (tid < 388) sCup[tid - 384] = 0.f;
  if (tid < 256) {
    shie[tid] = hie[(size_t)bi * 256 + tid];
    shix[tid] = hix[(size_t)bi * 256 + tid];
    slaste[tid] = We1[576 * 256 + tid];
    slastx[tid] = Wx1[576 * 256 + tid];
  }
  if (tid >= 448) {
    int j = tid - 448;
    int jg = jg0 + j;
    float dx = cix - coords[jg * 3 + 0];
    float dy = ciy - coords[jg * 3 + 1];
    float dz = ciz - coords[jg * 3 + 2];
    sqv[j] = dx * dx + dy * dy + dz * dz;
  }
  if (tid >= 384 && tid < 448)
    sAdj[tid - 384] = adjm[(size_t)bi * 128 + j0g + (tid - 384)];
  const float* efb = ef + ((size_t)bi * 128 + j0g) * 64;
  #pragma unroll
  for (int it = 0; it < 2; it++) {
    int idx = (tid + it * 512) * 4;
    f32x4 v = *(const f32x4*)(efb + idx);
    bf16x4 pk;
    pk[0] = tobf(v[0]); pk[1] = tobf(v[1]); pk[2] = tobf(v[2]); pk[3] = tobf(v[3]);
    *(bf16x4*)(sE + (idx >> 6) * 72 + (idx & 63)) = pk;
  }
  __syncthreads();

  egnn_path<true>(tid, sE, sSb, shie, slaste, sqv, sAdj,
                  hje + (size_t)jg0 * 256, wt_e, w2e, be2, Watt,
                  sRedE, batt[0], sNM, sCup, coords, jg0, cix, ciy, ciz);
  egnn_path<false>(tid, sE, sSb, shix, slastx, sqv, sAdj,
                   hjx + (size_t)jg0 * 256, wt_x, w2x, bx2, Wx3,
                   sRedX, bx3[0], sNM, sCup, coords, jg0, cix, ciy, ciz);

  __syncthreads();
  if (tid < 256) atomicAdd(&nmsg[(size_t)bi * 256 + tid], sNM[tid]);
  if (tid < 3) atomicAdd(&cupd[bi * 3 + tid], sCup[tid]);
}

extern "C" void kernel_launch(void* const* d_in, const int* in_sizes, int n_in,
                              void* d_out, int out_size, void* d_ws, size_t ws_size,
                              hipStream_t stream)
{
  const float* coords = (const float*)d_in[0];
  const float* invf  = (const float*)d_in[1];
  const float* adjm  = (const float*)d_in[2];
  const float* amask = (const float*)d_in[3];
  const float* ef    = (const float*)d_in[4];
  const float* We1   = (const float*)d_in[5];
  const float* be1   = (const float*)d_in[6];
  const float* We2   = (const float*)d_in[7];
  const float* be2   = (const float*)d_in[8];
  const float* Watt  = (const float*)d_in[9];
  const float* batt  = (const float*)d_in[10];
  const float* Wh1   = (const float*)d_in[11];
  const float* bh1   = (const float*)d_in[12];
  const float* Wh2   = (const float*)d_in[13];
  const float* bh2   = (const float*)d_in[14];
  const float* Wx1   = (const float*)d_in[15];
  const float* bx1   = (const float*)d_in[16];
  const float* Wx2   = (const float*)d_in[17];
  const float* bx2   = (const float*)d_in[18];
  const float* Wx3   = (const float*)d_in[19];
  const float* bx3   = (const float*)d_in[20];

  char* ws = (char*)d_ws;
  const size_t MB = 1u << 20;
  float* hie  = (float*)(ws + 0 * MB);
  float* hje  = (float*)(ws + 1 * MB);
  float* hix  = (float*)(ws + 2 * MB);
  float* hjx  = (float*)(ws + 3 * MB);
  __bf16* hcat = (__bf16*)(ws + 4 * MB);                 // [1024][512]
  __bf16* h1b  = (__bf16*)(ws + 5 * MB);                 // [1024][256]
  size_t woff = 5 * MB + 524288;
  __bf16* wt_e = (__bf16*)(ws + woff);                   // [256][576]
  __bf16* wt_x = (__bf16*)(ws + woff + 294912);
  __bf16* w2e  = (__bf16*)(ws + woff + 2 * 294912);
  __bf16* w2x  = (__bf16*)(ws + woff + 2 * 294912 + 131072);
  __bf16* wh1t = (__bf16*)(ws + woff + 2 * 294912 + 2 * 131072);
  __bf16* wh2t = (__bf16*)(ws + woff + 2 * 294912 + 2 * 131072 + 262144);
  float* nmsg  = (float*)(ws + woff + 2 * 294912 + 3 * 131072 + 262144);   // 1 MB
  float* cupd  = (float*)(ws + woff + 2 * 294912 + 3 * 131072 + 262144 + 1048576);

  float* out_coords = (float*)d_out;
  float* out_feats  = out_coords + 8 * 128 * 3;

  hipLaunchKernelGGL(k_prep, dim3(1024), dim3(256), 0, stream,
                     We1, Wx1, We2, Wx2, Wh1, Wh2, invf,
                     wt_e, wt_x, w2e, w2x, wh1t, wh2t, hcat, nmsg, cupd);
  hipLaunchKernelGGL(k_nproj, dim3(16, 4), dim3(256), 0, stream,
                     hcat, wt_e, wt_x, be1, bx1, hie, hje, hix, hjx);
  hipLaunchKernelGGL(k_edge, dim3(2048), dim3(512), 0, stream,
                     coords, adjm, ef, We1, Wx1, batt, be2, bx2, bx3, Watt, Wx3,
                     hie, hje, hix, hjx, wt_e, wt_x, w2e, w2x, nmsg, cupd);
  hipLaunchKernelGGL(k_mid, dim3(1024), dim3(256), 0, stream, nmsg, hcat);
  hipLaunchKernelGGL(k_h1, dim3(16), dim3(256), 0, stream,
                     hcat, wh1t, bh1, h1b);
  hipLaunchKernelGGL(k_h2, dim3(16), dim3(256), 0, stream,
                     h1b, wh2t, bh2, amask, coords, cupd, out_feats, out_coords);
}

// Round 6
// 187.583 us; speedup vs baseline: 1.5224x; 1.3487x over previous
//
#include <hip/hip_runtime.h>

typedef __attribute__((ext_vector_type(8))) __bf16 bf16x8;
typedef __attribute__((ext_vector_type(4))) __bf16 bf16x4;
typedef __attribute__((ext_vector_type(4))) float f32x4;

__device__ __forceinline__ float fast_sig(float x) {
  return __builtin_amdgcn_rcpf(1.0f + __expf(-x));
}
__device__ __forceinline__ float siluf(float x) { return x * fast_sig(x); }
__device__ __forceinline__ __bf16 tobf(float x) { return (__bf16)x; }

// async 16B global->LDS: LDS dest is wave-uniform base + lane*16; global src per-lane.
__device__ __forceinline__ void stage16(const void* g, void* l) {
  __builtin_amdgcn_global_load_lds(
      (const __attribute__((address_space(1))) void*)g,
      (__attribute__((address_space(3))) void*)l, 16, 0, 0);
}

// stage one [256 row][32 k] bf16 slice (16 KB) from src(row-major, ld elems, col off)
// into swbuf, with slot pre-swizzle: linear slot s of row c holds k-part (s ^ ((c>>1)&3)).
__device__ __forceinline__ void stage_slice(
    const __bf16* __restrict__ src, int ld, int off,
    __bf16* swbuf, int tid)
{
  const int w = tid >> 6;
  #pragma unroll
  for (int q = 0; q < 2; q++) {
    int t16 = q * 512 + tid;                 // 16B-unit index
    int c = t16 >> 2, slot = t16 & 3;
    int kpart = slot ^ ((c >> 1) & 3);
    const __bf16* g = src + (size_t)c * ld + off + kpart * 8;
    __bf16* l = swbuf + (size_t)(q * 512 + w * 64) * 8;   // wave-uniform base
    stage16(g, l);
  }
}

// ================= k_prep: weight transposes to bf16 [out][k] + WS zeroing =================
__global__ __launch_bounds__(256) void k_prep(
    const float* __restrict__ We1, const float* __restrict__ Wx1,
    const float* __restrict__ We2, const float* __restrict__ Wx2,
    const float* __restrict__ Wh1, const float* __restrict__ Wh2,
    const float* __restrict__ invf,
    __bf16* __restrict__ wt_e, __bf16* __restrict__ wt_x,
    __bf16* __restrict__ w2e, __bf16* __restrict__ w2x,
    __bf16* __restrict__ wh1t, __bf16* __restrict__ wh2t,
    __bf16* __restrict__ hcat,
    float* __restrict__ nmsg, float* __restrict__ cupd)
{
  int idx = blockIdx.x * 256 + threadIdx.x;          // 0..262143
  if (idx < 147456) {                                // [256 kk][576 f]
    int kk = idx / 576, f = idx - kk * 576;
    wt_e[idx] = tobf(We1[f * 256 + kk]);
    wt_x[idx] = tobf(Wx1[f * 256 + kk]);
  }
  if (idx < 65536) {                                 // [256 c][256 k]
    int c = idx >> 8, k = idx & 255;
    w2e[idx] = tobf(We2[k * 256 + c]);
    w2x[idx] = tobf(Wx2[k * 256 + c]);
    wh2t[idx] = tobf(Wh2[k * 256 + c]);
    f32x4 z = {0.f, 0.f, 0.f, 0.f};
    *(f32x4*)(nmsg + idx * 4) = z;                   // zero nmsg (262144 floats)
  }
  if (idx < 131072) {                                // [256 c][512 k]
    int c = idx >> 9, k = idx & 511;
    wh1t[idx] = tobf(Wh1[k * 256 + c]);
  }
  if (idx < 3072) cupd[idx] = 0.f;
  {                                                  // hcat[:,0:256] = bf16(invf)
    int node = idx >> 8, k = idx & 255;
    hcat[node * 512 + k] = tobf(invf[idx]);
  }
}

// ============ generic node GEMM: 64-row tile, 256 thr, out[c][node], no LDS ============
template<int NKS>
__device__ __forceinline__ void node_gemm64(
    const __bf16* __restrict__ B, int ldb, int boff,
    const __bf16* __restrict__ A, int lda, int aoff,
    int row0, int tid, f32x4 acc[4][4])
{
  const int lane = tid & 63, wc = tid >> 6, lr = lane & 15, lg = lane >> 4;
  #pragma unroll
  for (int ks = 0; ks < NKS; ks++) {
    bf16x8 bB[4], aA[4];
    #pragma unroll
    for (int m = 0; m < 4; m++)
      bB[m] = *(const bf16x8*)(B + (size_t)(row0 + m * 16 + lr) * ldb + boff + ks * 32 + lg * 8);
    #pragma unroll
    for (int n = 0; n < 4; n++)
      aA[n] = *(const bf16x8*)(A + (size_t)(wc * 64 + n * 16 + lr) * lda + aoff + ks * 32 + lg * 8);
    #pragma unroll
    for (int m = 0; m < 4; m++)
      #pragma unroll
      for (int n = 0; n < 4; n++)
        acc[m][n] = __builtin_amdgcn_mfma_f32_16x16x32_bf16(aA[n], bB[m], acc[m][n], 0, 0, 0);
  }
}

// ================= node projections (4 mats) =================
__global__ __launch_bounds__(256) void k_nproj(
    const __bf16* __restrict__ hcat,
    const __bf16* __restrict__ wt_e, const __bf16* __restrict__ wt_x,
    const float* __restrict__ be1, const float* __restrict__ bx1,
    float* __restrict__ hie, float* __restrict__ hje,
    float* __restrict__ hix, float* __restrict__ hjx)
{
  const int tid = threadIdx.x;
  const int row0 = blockIdx.x * 64;
  const int mat = blockIdx.y;
  const __bf16* A = (mat < 2) ? wt_e : wt_x;
  const int aoff = (mat & 1) ? 256 : 0;
  const float* bias = (mat == 0) ? be1 : (mat == 2 ? bx1 : nullptr);
  float* out = (mat == 0) ? hie : (mat == 1) ? hje : (mat == 2) ? hix : hjx;

  f32x4 acc[4][4];
  #pragma unroll
  for (int m = 0; m < 4; m++)
    #pragma unroll
    for (int n = 0; n < 4; n++) { f32x4 z = {0.f,0.f,0.f,0.f}; acc[m][n] = z; }
  node_gemm64<8>(hcat, 512, 0, A, 576, aoff, row0, tid, acc);

  const int lane = tid & 63, wc = tid >> 6, lr = lane & 15, lg = lane >> 4;
  #pragma unroll
  for (int m = 0; m < 4; m++) {
    int node = row0 + m * 16 + lr;
    #pragma unroll
    for (int n = 0; n < 4; n++) {
      int c0 = wc * 64 + n * 16 + lg * 4;
      f32x4 v = acc[m][n];
      if (bias) v += *(const f32x4*)(bias + c0);
      *(f32x4*)(out + (size_t)node * 256 + c0) = v;
    }
  }
}

// ================= k_mid: nmsg fp32 -> hcat upper half bf16 =================
__global__ __launch_bounds__(256) void k_mid(
    const float* __restrict__ nmsg, __bf16* __restrict__ hcat)
{
  int idx = blockIdx.x * 256 + threadIdx.x;   // 262144
  int node = idx >> 8, k = idx & 255;
  hcat[node * 512 + 256 + k] = tobf(nmsg[idx]);
}

// ================= h-path GEMM1 =================
__global__ __launch_bounds__(256) void k_h1(
    const __bf16* __restrict__ hcat, const __bf16* __restrict__ wh1t,
    const float* __restrict__ bh1, __bf16* __restrict__ h1b)
{
  const int tid = threadIdx.x;
  const int row0 = blockIdx.x * 64;
  f32x4 acc[4][4];
  #pragma unroll
  for (int m = 0; m < 4; m++)
    #pragma unroll
    for (int n = 0; n < 4; n++) { f32x4 z = {0.f,0.f,0.f,0.f}; acc[m][n] = z; }
  node_gemm64<16>(hcat, 512, 0, wh1t, 512, 0, row0, tid, acc);

  const int lane = tid & 63, wc = tid >> 6, lr = lane & 15, lg = lane >> 4;
  #pragma unroll
  for (int m = 0; m < 4; m++) {
    int node = row0 + m * 16 + lr;
    #pragma unroll
    for (int n = 0; n < 4; n++) {
      int c0 = wc * 64 + n * 16 + lg * 4;
      f32x4 b4 = *(const f32x4*)(bh1 + c0);
      bf16x4 pk;
      #pragma unroll
      for (int r = 0; r < 4; r++) pk[r] = tobf(siluf(acc[m][n][r] + b4[r]));
      *(bf16x4*)(h1b + (size_t)node * 256 + c0) = pk;
    }
  }
}

// ===== h-path GEMM2 + mask + coord finalize =====
__global__ __launch_bounds__(256) void k_h2(
    const __bf16* __restrict__ h1b, const __bf16* __restrict__ wh2t,
    const float* __restrict__ bh2, const float* __restrict__ amask,
    const float* __restrict__ coords, const float* __restrict__ cupd,
    float* __restrict__ out_feats, float* __restrict__ out_coords)
{
  __shared__ float sM[2];
  const int tid = threadIdx.x;
  const int row0 = blockIdx.x * 64;
  const int b = row0 >> 7;
  f32x4 acc[4][4];
  #pragma unroll
  for (int m = 0; m < 4; m++)
    #pragma unroll
    for (int n = 0; n < 4; n++) { f32x4 z = {0.f,0.f,0.f,0.f}; acc[m][n] = z; }
  node_gemm64<8>(h1b, 256, 0, wh2t, 256, 0, row0, tid, acc);

  if (tid < 128) {
    float v = amask[b * 128 + tid];
    #pragma unroll
    for (int off = 1; off < 64; off <<= 1) v += __shfl_xor(v, off);
    if ((tid & 63) == 0) sM[tid >> 6] = v;
  }
  __syncthreads();
  const float sNum = sM[0] + sM[1];

  const int lane = tid & 63, wc = tid >> 6, lr = lane & 15, lg = lane >> 4;
  #pragma unroll
  for (int m = 0; m < 4; m++) {
    int node = row0 + m * 16 + lr;
    float msk = amask[node];
    #pragma unroll
    for (int n = 0; n < 4; n++) {
      int c0 = wc * 64 + n * 16 + lg * 4;
      f32x4 b4 = *(const f32x4*)(bh2 + c0);
      f32x4 v = (acc[m][n] + b4) * msk;
      *(f32x4*)(out_feats + (size_t)node * 256 + c0) = v;
    }
  }
  if (tid < 192) {
    int nl = tid / 3, d = tid - nl * 3;
    int node = row0 + nl;
    float upd = cupd[node * 3 + d] / (sNum + 1.0f);
    out_coords[node * 3 + d] = (coords[node * 3 + d] + upd) * amask[node];
  }
}

// ========== edge-MLP path, async-staged weights, one 64-j half, 512 thr ==========
template<bool EPATH>
__device__ __forceinline__ void egnn_path(
    int tid, char* sSb, __bf16* sW0, __bf16* sW1,
    const float* shi, const float* slast, const float* sqv, const float* sAdj,
    const float* __restrict__ hjb,          // + jg0*256
    const __bf16* __restrict__ wt,          // [256 kk][576 f]
    const __bf16* __restrict__ w2,          // [256 c][256 k]
    const float* __restrict__ bias2, const float* __restrict__ vvec,
    float* sRed, float batt0, float* sNM, float* sCup,
    const float* __restrict__ coords, int jg0,
    float cix, float ciy, float ciz, const bf16x8 bE[2][2])
{
  const int lane = tid & 63, w = tid >> 6;
  const int lr = lane & 15, lg = lane >> 4;
  const int cg = (w & 3) * 64;       // 4 c-waves x 64
  const int jw = (w >> 2) * 32;      // 2 j-waves x 32
  const int slot = lg ^ ((lr >> 1) & 3);
  const int awbase = (cg + lr) * 32 + slot * 8;   // + n*512 elems

  // stage GEMM1 slice 0 (lands by entry barrier)
  stage_slice(wt, 576, 512, sW0, tid);

  // preload hj fragments (register, overlaps stage latency)
  f32x4 hjf[2][4];
  #pragma unroll
  for (int m = 0; m < 2; m++) {
    const int jl = jw + m * 16 + lr;
    #pragma unroll
    for (int n = 0; n < 4; n++)
      hjf[m][n] = *(const f32x4*)(hjb + (size_t)jl * 256 + cg + n * 16 + lg * 4);
  }

  f32x4 acc[2][4];
  #pragma unroll
  for (int m = 0; m < 2; m++)
    #pragma unroll
    for (int n = 0; n < 4; n++) { f32x4 z = {0.f,0.f,0.f,0.f}; acc[m][n] = z; }

  __syncthreads();   // slice0 landed; prev phase's LDS reads done

  // ---- GEMM1 step 0 ----
  stage_slice(wt, 576, 544, sW1, tid);
  {
    bf16x8 aW[4];
    #pragma unroll
    for (int n = 0; n < 4; n++) aW[n] = *(const bf16x8*)(sW0 + awbase + n * 512);
    #pragma unroll
    for (int m = 0; m < 2; m++)
      #pragma unroll
      for (int n = 0; n < 4; n++)
        acc[m][n] = __builtin_amdgcn_mfma_f32_16x16x32_bf16(aW[n], bE[0][m], acc[m][n], 0, 0, 0);
  }
  __syncthreads();

  // ---- GEMM1 step 1 + ep1 ----
  stage_slice(w2, 256, 0, sW0, tid);
  {
    bf16x8 aW[4];
    #pragma unroll
    for (int n = 0; n < 4; n++) aW[n] = *(const bf16x8*)(sW1 + awbase + n * 512);
    #pragma unroll
    for (int m = 0; m < 2; m++)
      #pragma unroll
      for (int n = 0; n < 4; n++)
        acc[m][n] = __builtin_amdgcn_mfma_f32_16x16x32_bf16(aW[n], bE[1][m], acc[m][n], 0, 0, 0);
  }
  // ep1: + hi + hj + sq*w_last, silu, bf16 -> swizzled sSb; then reset acc
  #pragma unroll
  for (int m = 0; m < 2; m++) {
    const int jl = jw + m * 16 + lr;
    const float sq = sqv[jl];
    #pragma unroll
    for (int n = 0; n < 4; n++) {
      const int kk0 = cg + n * 16 + lg * 4;
      f32x4 hi4 = *(const f32x4*)(shi + kk0);
      f32x4 sl4 = *(const f32x4*)(slast + kk0);
      bf16x4 pk;
      #pragma unroll
      for (int r = 0; r < 4; r++)
        pk[r] = tobf(siluf(acc[m][n][r] + hi4[r] + hjf[m][n][r] + sq * sl4[r]));
      int off = (jl * 512 + kk0 * 2) ^ ((jl & 7) << 4);
      *(bf16x4*)(sSb + off) = pk;
      f32x4 z = {0.f, 0.f, 0.f, 0.f};
      acc[m][n] = z;
    }
  }
  __syncthreads();

  // ---- GEMM2: 8 k-steps, double-buffered weight staging ----
  #pragma unroll
  for (int ks = 0; ks < 8; ks++) {
    if (ks < 7)
      stage_slice(w2, 256, (ks + 1) * 32, (ks & 1) ? sW0 : sW1, tid);
    const __bf16* sw = (ks & 1) ? sW1 : sW0;
    bf16x8 aW[4], bS[2];
    #pragma unroll
    for (int m = 0; m < 2; m++) {
      const int jl = jw + m * 16 + lr;
      int off = (jl * 512 + (ks * 32 + lg * 8) * 2) ^ ((jl & 7) << 4);
      bS[m] = *(const bf16x8*)(sSb + off);
    }
    #pragma unroll
    for (int n = 0; n < 4; n++) aW[n] = *(const bf16x8*)(sw + awbase + n * 512);
    #pragma unroll
    for (int m = 0; m < 2; m++)
      #pragma unroll
      for (int n = 0; n < 4; n++)
        acc[m][n] = __builtin_amdgcn_mfma_f32_16x16x32_bf16(aW[n], bS[m], acc[m][n], 0, 0, 0);
    __syncthreads();
  }

  // ep2: silu(+bias2), dot with vvec -> sRed[j]
  float p[2] = {0.f, 0.f};
  #pragma unroll
  for (int n = 0; n < 4; n++) {
    f32x4 bb = *(const f32x4*)(bias2 + cg + n * 16 + lg * 4);
    f32x4 vv = *(const f32x4*)(vvec  + cg + n * 16 + lg * 4);
    #pragma unroll
    for (int m = 0; m < 2; m++)
      #pragma unroll
      for (int r = 0; r < 4; r++) {
        float s = siluf(acc[m][n][r] + bb[r]);
        acc[m][n][r] = s;
        p[m] += s * vv[r];
      }
  }
  #pragma unroll
  for (int m = 0; m < 2; m++) {
    p[m] += __shfl_xor(p[m], 16);
    p[m] += __shfl_xor(p[m], 32);
  }
  if (lane < 16) {
    #pragma unroll
    for (int m = 0; m < 2; m++)
      atomicAdd(&sRed[jw + m * 16 + lr], p[m]);
  }
  __syncthreads();

  if constexpr (EPATH) {
    float aw[2];
    #pragma unroll
    for (int m = 0; m < 2; m++) {
      int jl = jw + m * 16 + lr;
      aw[m] = fast_sig(sRed[jl] + batt0) * sAdj[jl];
    }
    f32x4 q[4];
    #pragma unroll
    for (int n = 0; n < 4; n++) { f32x4 z = {0.f,0.f,0.f,0.f}; q[n] = z; }
    #pragma unroll
    for (int m = 0; m < 2; m++)
      #pragma unroll
      for (int n = 0; n < 4; n++)
        q[n] += acc[m][n] * aw[m];
    #pragma unroll
    for (int off = 1; off < 16; off <<= 1)
      #pragma unroll
      for (int n = 0; n < 4; n++)
        #pragma unroll
        for (int r = 0; r < 4; r++)
          q[n][r] += __shfl_xor(q[n][r], off);
    if (lr == 0) {
      #pragma unroll
      for (int n = 0; n < 4; n++)
        #pragma unroll
        for (int r = 0; r < 4; r++)
          atomicAdd(&sNM[cg + n * 16 + lg * 4 + r], q[n][r]);
    }
  } else {
    if (tid < 64) {
      int jl = tid;
      int jgl = jg0 + jl;
      float ea = sRed[jl] + batt0;
      float wgt = ea * __builtin_amdgcn_rcpf(sqrtf(sqv[jl] + 1e-5f) + 1.0f) * sAdj[jl];
      float wx = wgt * (cix - coords[jgl * 3 + 0]);
      float wy = wgt * (ciy - coords[jgl * 3 + 1]);
      float wz = wgt * (ciz - coords[jgl * 3 + 2]);
      #pragma unroll
      for (int off = 1; off < 64; off <<= 1) {
        wx += __shfl_xor(wx, off);
        wy += __shfl_xor(wy, off);
        wz += __shfl_xor(wz, off);
      }
      if (tid == 0) { sCup[0] = wx; sCup[1] = wy; sCup[2] = wz; }
    }
  }
}

// ======== main edge kernel: one block = one (b,i)-HALF (64 j), 512 thr ========
__global__ __launch_bounds__(512, 4) void k_edge(
    const float* __restrict__ coords, const float* __restrict__ adjm,
    const float* __restrict__ ef,
    const float* __restrict__ We1, const float* __restrict__ Wx1,
    const float* __restrict__ batt,
    const float* __restrict__ be2, const float* __restrict__ bx2,
    const float* __restrict__ bx3,
    const float* __restrict__ Watt, const float* __restrict__ Wx3,
    const float* __restrict__ hie, const float* __restrict__ hje,
    const float* __restrict__ hix, const float* __restrict__ hjx,
    const __bf16* __restrict__ wt_e, const __bf16* __restrict__ wt_x,
    const __bf16* __restrict__ w2e, const __bf16* __restrict__ w2x,
    float* __restrict__ nmsg, float* __restrict__ cupd)
{
  __shared__ __align__(16) char sSb[64 * 512];            // 32 KB
  __shared__ __align__(16) __bf16 sW[2][8192];            // 32 KB weight dbuf
  __shared__ float shie[256], shix[256], slaste[256], slastx[256];
  __shared__ float sqv[64], sAdj[64], sRedE[64], sRedX[64], sNM[256], sCup[4];

  const int tid = threadIdx.x;
  const int bi = blockIdx.x >> 1;      // b*128 + i
  const int half = blockIdx.x & 1;
  const int b = bi >> 7;
  const int j0g = half * 64;
  const int jg0 = b * 128 + j0g;

  const int lane = tid & 63, w = tid >> 6;
  const int lr = lane & 15, lg = lane >> 4;
  const int jw = (w >> 2) * 32;

  const float cix = coords[bi * 3 + 0];
  const float ciy = coords[bi * 3 + 1];
  const float ciz = coords[bi * 3 + 2];

  if (tid < 64) sRedE[tid] = 0.f;
  else if (tid < 128) sRedX[tid - 64] = 0.f;
  else if (tid < 384) sNM[tid - 128] = 0.f;
  else if (tid < 388) sCup[tid - 384] = 0.f;
  if (tid < 256) {
    shie[tid] = hie[(size_t)bi * 256 + tid];
    shix[tid] = hix[(size_t)bi * 256 + tid];
    slaste[tid] = We1[576 * 256 + tid];
    slastx[tid] = Wx1[576 * 256 + tid];
  }
  if (tid >= 448) {
    int j = tid - 448;
    int jg = jg0 + j;
    float dx = cix - coords[jg * 3 + 0];
    float dy = ciy - coords[jg * 3 + 1];
    float dz = ciz - coords[jg * 3 + 2];
    sqv[j] = dx * dx + dy * dy + dz * dz;
  }
  if (tid >= 384 && tid < 448)
    sAdj[tid - 384] = adjm[(size_t)bi * 128 + j0g + (tid - 384)];

  // E fragments in registers (shared by both paths)
  bf16x8 bE[2][2];
  {
    const float* efb = ef + ((size_t)bi * 128 + j0g) * 64;
    #pragma unroll
    for (int ks = 0; ks < 2; ks++)
      #pragma unroll
      for (int m = 0; m < 2; m++) {
        const float* er = efb + (jw + m * 16 + lr) * 64 + ks * 32 + lg * 8;
        f32x4 x = *(const f32x4*)er;
        f32x4 y = *(const f32x4*)(er + 4);
        bf16x8 t;
        t[0] = tobf(x[0]); t[1] = tobf(x[1]); t[2] = tobf(x[2]); t[3] = tobf(x[3]);
        t[4] = tobf(y[0]); t[5] = tobf(y[1]); t[6] = tobf(y[2]); t[7] = tobf(y[3]);
        bE[ks][m] = t;
      }
  }
  // NOTE: no barrier here; egnn_path's entry barrier covers prologue LDS writes.

  egnn_path<true>(tid, sSb, sW[0], sW[1], shie, slaste, sqv, sAdj,
                  hje + (size_t)jg0 * 256, wt_e, w2e, be2, Watt,
                  sRedE, batt[0], sNM, sCup, coords, jg0, cix, ciy, ciz, bE);
  egnn_path<false>(tid, sSb, sW[0], sW[1], shix, slastx, sqv, sAdj,
                   hjx + (size_t)jg0 * 256, wt_x, w2x, bx2, Wx3,
                   sRedX, bx3[0], sNM, sCup, coords, jg0, cix, ciy, ciz, bE);

  __syncthreads();
  if (tid < 256) atomicAdd(&nmsg[(size_t)bi * 256 + tid], sNM[tid]);
  if (tid < 3) atomicAdd(&cupd[bi * 3 + tid], sCup[tid]);
}

extern "C" void kernel_launch(void* const* d_in, const int* in_sizes, int n_in,
                              void* d_out, int out_size, void* d_ws, size_t ws_size,
                              hipStream_t stream)
{
  const float* coords = (const float*)d_in[0];
  const float* invf  = (const float*)d_in[1];
  const float* adjm  = (const float*)d_in[2];
  const float* amask = (const float*)d_in[3];
  const float* ef    = (const float*)d_in[4];
  const float* We1   = (const float*)d_in[5];
  const float* be1   = (const float*)d_in[6];
  const float* We2   = (const float*)d_in[7];
  const float* be2   = (const float*)d_in[8];
  const float* Watt  = (const float*)d_in[9];
  const float* batt  = (const float*)d_in[10];
  const float* Wh1   = (const float*)d_in[11];
  const float* bh1   = (const float*)d_in[12];
  const float* Wh2   = (const float*)d_in[13];
  const float* bh2   = (const float*)d_in[14];
  const float* Wx1   = (const float*)d_in[15];
  const float* bx1   = (const float*)d_in[16];
  const float* Wx2   = (const float*)d_in[17];
  const float* bx2   = (const float*)d_in[18];
  const float* Wx3   = (const float*)d_in[19];
  const float* bx3   = (const float*)d_in[20];

  char* ws = (char*)d_ws;
  const size_t MB = 1u << 20;
  float* hie  = (float*)(ws + 0 * MB);
  float* hje  = (float*)(ws + 1 * MB);
  float* hix  = (float*)(ws + 2 * MB);
  float* hjx  = (float*)(ws + 3 * MB);
  __bf16* hcat = (__bf16*)(ws + 4 * MB);                 // [1024][512]
  __bf16* h1b  = (__bf16*)(ws + 5 * MB);                 // [1024][256]
  size_t woff = 5 * MB + 524288;
  __bf16* wt_e = (__bf16*)(ws + woff);                   // [256][576]
  __bf16* wt_x = (__bf16*)(ws + woff + 294912);
  __bf16* w2e  = (__bf16*)(ws + woff + 2 * 294912);
  __bf16* w2x  = (__bf16*)(ws + woff + 2 * 294912 + 131072);
  __bf16* wh1t = (__bf16*)(ws + woff + 2 * 294912 + 2 * 131072);
  __bf16* wh2t = (__bf16*)(ws + woff + 2 * 294912 + 2 * 131072 + 262144);
  float* nmsg  = (float*)(ws + woff + 2 * 294912 + 3 * 131072 + 262144);   // 1 MB
  float* cupd  = (float*)(ws + woff + 2 * 294912 + 3 * 131072 + 262144 + 1048576);

  float* out_coords = (float*)d_out;
  float* out_feats  = out_coords + 8 * 128 * 3;

  hipLaunchKernelGGL(k_prep, dim3(1024), dim3(256), 0, stream,
                     We1, Wx1, We2, Wx2, Wh1, Wh2, invf,
                     wt_e, wt_x, w2e, w2x, wh1t, wh2t, hcat, nmsg, cupd);
  hipLaunchKernelGGL(k_nproj, dim3(16, 4), dim3(256), 0, stream,
                     hcat, wt_e, wt_x, be1, bx1, hie, hje, hix, hjx);
  hipLaunchKernelGGL(k_edge, dim3(2048), dim3(512), 0, stream,
                     coords, adjm, ef, We1, Wx1, batt, be2, bx2, bx3, Watt, Wx3,
                     hie, hje, hix, hjx, wt_e, wt_x, w2e, w2x, nmsg, cupd);
  hipLaunchKernelGGL(k_mid, dim3(1024), dim3(256), 0, stream, nmsg, hcat);
  hipLaunchKernelGGL(k_h1, dim3(16), dim3(256), 0, stream,
                     hcat, wh1t, bh1, h1b);
  hipLaunchKernelGGL(k_h2, dim3(16), dim3(256), 0, stream,
                     h1b, wh2t, bh2, amask, coords, cupd, out_feats, out_coords);
}